// Round 6
// baseline (31.539 us; speedup 1.0000x reference)
//
#include <hip/hip_runtime.h>

// RegpPooling2D, row-streamed 2D tile: 8 output rows x 8 cols per thread on a
// 10x10 input tile. Candidate rows swept top-to-bottom; each closeness check
// computed once and shared across all windows containing it (3v x 3h max).
// Only 3 output-row states live at once; rows stored when complete. Reference
// (ni,nj) per-window update order preserved exactly.

#define W_T 8
#define H_T 8
#define QC (W_T + 2)   // 10 tile cols
#define AR (H_T + 2)   // 10 tile rows

__global__ __launch_bounds__(256) void regp_pool_kernel(
    const float* __restrict__ x, float* __restrict__ out) {
    const int tx = blockIdx.x * blockDim.x + threadIdx.x;
    const int jt = tx & 15;          // 16 col-tiles of 8
    const int it = (tx >> 4) & 15;   // 16 row-tiles of 8
    const int bc = tx >> 8;          // 512 B*C
    const int i  = it * H_T;
    const int j  = jt * W_T;

    const float* __restrict__ src = x + (size_t)bc * (130 * 130) + i * 130 + j;
    float* __restrict__ dst = out + (size_t)bc * (128 * 128) + i * 128 + j;

    float win[AR][QC];
    // preload tile rows 0..2; row a+2 is fetched during iteration a
#pragma unroll
    for (int rr = 0; rr < 3; ++rr) {
#pragma unroll
        for (int qq = 0; qq < QC; qq += 2) {
            const float2 v = *reinterpret_cast<const float2*>(src + rr * 130 + qq);
            win[rr][qq]     = v.x;
            win[rr][qq + 1] = v.y;
        }
    }

    float p[H_T][W_T];
    int   mc[H_T][W_T];

    // sequential update, replicating reference order exactly
    auto upd = [](float& pp, int& mm, float c, int cv) {
        const bool  gt  = cv > mm;
        const float pn  = gt ? c : pp;
        const int   mcn = gt ? cv : mm;
        pp = (cv == mcn) ? (c + pn) * 0.5f : pn;
        mm = mcn;
    };

#pragma unroll
    for (int a = 0; a < AR; ++a) {   // candidate tile row
        // prefetch tile row a+2 (used starting next iteration)
        if (a >= 1 && a + 2 < AR) {
#pragma unroll
            for (int qq = 0; qq < QC; qq += 2) {
                const float2 v =
                    *reinterpret_cast<const float2*>(src + (a + 2) * 130 + qq);
                win[a + 2][qq]     = v.x;
                win[a + 2][qq + 1] = v.y;
            }
        }

        // output row a becomes live this iteration (first update is ni=0)
        if (a <= H_T - 1) {
#pragma unroll
            for (int w = 0; w < W_T; ++w) { p[a][w] = 0.0f; mc[a][w] = 0; }
        }

#pragma unroll
        for (int q = 0; q < QC; ++q) {   // candidate tile col
            const bool vR = (q <= W_T - 1);         // nj=0 valid (px=q)
            const bool vA = (q >= 1 && q <= W_T);   // nj=1 valid (px=q-1)
            const bool vL = (q >= 2);               // nj=2 valid (px=q-2)

            const float c = win[a][q];
            const float t = 0.3f * fabsf(c);
            const bool  zc = (c == 0.0f);
            const int corr3 = zc ? 2 : -1;   // 3*(c==0) - 1
            const int corr5 = zc ? 4 : -1;   // 5*(c==0) - 1

            // s[v][da+1]: column sums for nj-variant v at neighbor row a+da
            // v=0: cols {q,q+1}; v=1: {q-1..q+1}; v=2: {q-1,q}
            int s[3][3];
#pragma unroll
            for (int da = -1; da <= 1; ++da) {
                if (da == -1 && a < 1) continue;       // no role uses row a-1
                if (da ==  1 && a > H_T) continue;     // no role uses row a+1
                const int a2 = a + da;                 // in [0, AR-1] by above
                const int bl = (q >= 1 && (vA || vL))
                                   ? (int)(fabsf(win[a2][q - 1] - c) <= t) : 0;
                // self-check always true -> constant-folds
                const int bm = (da == 0) ? 1
                                         : (int)(fabsf(win[a2][q] - c) <= t);
                const int br = (q <= QC - 2 && (vR || vA))
                                   ? (int)(fabsf(win[a2][q + 1] - c) <= t) : 0;
                if (vR) s[0][da + 1] = bm + br;
                if (vA) s[1][da + 1] = bl + bm + br;
                if (vL) s[2][da + 1] = bl + bm;
            }

#pragma unroll
            for (int nj = 0; nj < 3; ++nj) {
                const bool vv = (nj == 0) ? vR : (nj == 1) ? vA : vL;
                if (!vv) continue;
                const int px = q - nj;   // target output column

                // shared partial row-sums (int adds: exact, order-free)
                int P12 = 0, P01 = 0;
                if (a <= H_T)
                    P12 = s[nj][1] + s[nj][2];   // rows {a, a+1}
                if (a >= 2)
                    P01 = s[nj][0] + s[nj][1];   // rows {a-1, a}

                // ni=0 -> output row a: neighbor rows {a, a+1}
                if (a <= H_T - 1)
                    upd(p[a][px], mc[a][px], c,
                        P12 + ((nj == 1) ? corr3 : corr5));
                // ni=1 -> output row a-1: neighbor rows {a-1, a, a+1}
                if (a >= 1 && a <= H_T)
                    upd(p[a - 1][px], mc[a - 1][px], c,
                        P12 + s[nj][0] + ((nj == 1) ? -1 : corr3));
                // ni=2 -> output row a-2: neighbor rows {a-1, a}
                if (a >= 2)
                    upd(p[a - 2][px], mc[a - 2][px], c,
                        P01 + ((nj == 1) ? corr3 : corr5));
            }
        }

        // output row a-2 received its last update (ni=2) this iteration
        if (a >= 2) {
            const int r = a - 2;
            float4 oa, ob;
            oa.x = p[r][0]; oa.y = p[r][1]; oa.z = p[r][2]; oa.w = p[r][3];
            ob.x = p[r][4]; ob.y = p[r][5]; ob.z = p[r][6]; ob.w = p[r][7];
            *reinterpret_cast<float4*>(dst + r * 128)     = oa;
            *reinterpret_cast<float4*>(dst + r * 128 + 4) = ob;
        }
    }
}

extern "C" void kernel_launch(void* const* d_in, const int* in_sizes, int n_in,
                              void* d_out, int out_size, void* d_ws, size_t ws_size,
                              hipStream_t stream) {
    const float* x   = (const float*)d_in[0];
    float*       out = (float*)d_out;
    const int threads = 256;
    const int total_threads = out_size / (H_T * W_T);   // 131072
    const int blocks  = total_threads / threads;        // 512
    regp_pool_kernel<<<blocks, threads, 0, stream>>>(x, out);
}